// Round 12
// baseline (326.103 us; speedup 1.0000x reference)
//
#include <hip/hip_runtime.h>

typedef unsigned short u16;
typedef unsigned int   u32;

#define HW 4096
#define NC 128

typedef __bf16 bf16x8 __attribute__((ext_vector_type(8)));
typedef float  f32x16 __attribute__((ext_vector_type(16)));

__device__ __forceinline__ bf16x8 as_bf8(uint4 u){
    union { uint4 u; bf16x8 b; } c; c.u = u; return c.b;
}
__device__ __forceinline__ u16 f2bf(float f){
    u32 u = __float_as_uint(f);
    return (u16)((u + 0x7fffu + ((u >> 16) & 1u)) >> 16);
}
__device__ __forceinline__ u32 pack2(float a, float b){
    return ((__float_as_uint(a) + 0x8000u) >> 16) | ((__float_as_uint(b) + 0x8000u) & 0xffff0000u);
}
__device__ __forceinline__ float bf_lo(u32 u){ return __uint_as_float(u << 16); }
__device__ __forceinline__ float bf_hi(u32 u){ return __uint_as_float(u & 0xffff0000u); }
__device__ __forceinline__ void unpack8(uint4 u, float* v){
    v[0]=bf_lo(u.x); v[1]=bf_hi(u.x); v[2]=bf_lo(u.y); v[3]=bf_hi(u.y);
    v[4]=bf_lo(u.z); v[5]=bf_hi(u.z); v[6]=bf_lo(u.w); v[7]=bf_hi(u.w);
}

// 2^x via the HW transcendental unit (avoid glibc __exp2f macro collision)
__device__ __forceinline__ float exp2_hw(float x){ return __builtin_amdgcn_exp2f(x); }

// ---------------- K1: fused GroupNorm partial sums + weight prep ----------------
__global__ __launch_bounds__(256) void gnw_kernel(const float* __restrict__ x,
                                                  float* __restrict__ stats,
                                                  const float* __restrict__ qkv_w,
                                                  const float* __restrict__ proj_w,
                                                  uint4* __restrict__ Wf,
                                                  uint4* __restrict__ Pf){
    if (blockIdx.x < 256){
        int bg = blockIdx.x >> 3, part = blockIdx.x & 7;
        const float4* p = (const float4*)(x + (size_t)bg * 65536 + part * 8192);
        float s = 0.f, ss = 0.f;
        #pragma unroll
        for (int i = 0; i < 8; i++){
            float4 u = p[threadIdx.x + i*256];
            s  += u.x + u.y + u.z + u.w;
            ss += u.x*u.x + u.y*u.y + u.z*u.z + u.w*u.w;
        }
        #pragma unroll
        for (int off = 32; off > 0; off >>= 1){
            s  += __shfl_xor(s,  off);
            ss += __shfl_xor(ss, off);
        }
        __shared__ float rs[4], rss[4];
        int wid = threadIdx.x >> 6;
        if ((threadIdx.x & 63) == 0){ rs[wid] = s; rss[wid] = ss; }
        __syncthreads();
        if (threadIdx.x == 0){
            stats[bg*16 + part*2]     = rs[0]+rs[1]+rs[2]+rs[3];
            stats[bg*16 + part*2 + 1] = rss[0]+rss[1]+rss[2]+rss[3];
        }
    } else {
        int id = (blockIdx.x - 256)*256 + threadIdx.x;   // 0..8191
        const float* src; uint4* dst; int fi;
        if (id < 6144){ src = qkv_w; dst = Wf; fi = id; }
        else          { src = proj_w; dst = Pf; fi = id - 6144; }
        int l = fi & 63, ks = (fi >> 6) & 7, ob = fi >> 9;
        int o = ob*32 + (l & 31);
        int c = ks*16 + ((l >> 5) << 3);
        const float* s = src + o*128 + c;
        dst[fi] = make_uint4(pack2(s[0],s[1]), pack2(s[2],s[3]), pack2(s[4],s[5]), pack2(s[6],s[7]));
    }
}

// ---------------- K2: MFMA GN+QKV. grid 512 (b = x>>7, tokblk = x&127), block 256 ----------------
__global__ __launch_bounds__(256) void qkv_kernel(const float* __restrict__ x,
                                                  const float* __restrict__ stats,
                                                  const float* __restrict__ gamma,
                                                  const float* __restrict__ beta,
                                                  const uint4* __restrict__ Wf,
                                                  const float* __restrict__ bias,
                                                  uint4* __restrict__ Qf,
                                                  uint4* __restrict__ Kf,
                                                  uint4* __restrict__ Vf){
    __shared__ float gaL[128], beL[128], biasL[384];
    int b = blockIdx.x >> 7, tokblk = blockIdx.x & 127;
    int t = threadIdx.x, lane = t & 63, wv = t >> 6;
    if (t < 128){
        int g = t >> 4;
        float S = 0.f, SS = 0.f;
        #pragma unroll
        for (int p = 0; p < 8; p++){
            S  += stats[(b*8 + g)*16 + p*2];
            SS += stats[(b*8 + g)*16 + p*2 + 1];
        }
        float mean = S * (1.f/65536.f);
        float rstd = rsqrtf(SS * (1.f/65536.f) - mean*mean + 1e-5f);
        float ga = gamma[t] * rstd;
        gaL[t] = ga; beL[t] = beta[t] - mean*ga;
    }
    if (t < 192){ biasL[t] = bias[t]; biasL[t+192] = bias[t+192]; }
    __syncthreads();

    int h = lane >> 5, tl = lane & 31;
    uint4 xf[8];
    const float* xb = x + (size_t)b*128*HW + tokblk*32 + tl;
    #pragma unroll
    for (int ks = 0; ks < 8; ks++){
        int c0 = ks*16 + h*8;
        float4 g0 = *(float4*)&gaL[c0], g1 = *(float4*)&gaL[c0+4];
        float4 e0 = *(float4*)&beL[c0], e1 = *(float4*)&beL[c0+4];
        float v[8];
        #pragma unroll
        for (int j = 0; j < 8; j++) v[j] = xb[(size_t)(c0+j)*HW];
        v[0] = fmaf(v[0], g0.x, e0.x); v[1] = fmaf(v[1], g0.y, e0.y);
        v[2] = fmaf(v[2], g0.z, e0.z); v[3] = fmaf(v[3], g0.w, e0.w);
        v[4] = fmaf(v[4], g1.x, e1.x); v[5] = fmaf(v[5], g1.y, e1.y);
        v[6] = fmaf(v[6], g1.z, e1.z); v[7] = fmaf(v[7], g1.w, e1.w);
        xf[ks] = make_uint4(pack2(v[0],v[1]), pack2(v[2],v[3]), pack2(v[4],v[5]), pack2(v[6],v[7]));
    }

    bool up = (lane >= 32);
    #pragma unroll
    for (int i = 0; i < 3; i++){
        int ob = wv*3 + i;
        uint4 wf[8];
        #pragma unroll
        for (int ks = 0; ks < 8; ks++) wf[ks] = Wf[(ob*8 + ks)*64 + lane];
        f32x16 D;
        #pragma unroll
        for (int r = 0; r < 16; r++) D[r] = 0.f;
        if (ob < 8){
            #pragma unroll
            for (int ks = 0; ks < 8; ks++)
                D = __builtin_amdgcn_mfma_f32_32x32x16_bf16(as_bf8(wf[ks]), as_bf8(xf[ks]), D, 0,0,0);
            #pragma unroll
            for (int r = 0; r < 16; r++)
                D[r] += biasL[ob*32 + (r&3) + 8*(r>>2) + 4*h];
            u32 pk[8], xch[8];
            #pragma unroll
            for (int j = 0; j < 8; j++) pk[j] = pack2(D[2*j], D[2*j+1]);
            #pragma unroll
            for (int j = 0; j < 8; j++) xch[j] = __shfl_xor(pk[j], 32);
            uint4 F0 = up ? make_uint4(xch[2],xch[3],pk[2],pk[3]) : make_uint4(pk[0],pk[1],xch[0],xch[1]);
            uint4 F1 = up ? make_uint4(xch[6],xch[7],pk[6],pk[7]) : make_uint4(pk[4],pk[5],xch[4],xch[5]);
            uint4* dst = (ob < 4) ? Qf : Kf;
            int obl = ob & 3;
            size_t base = (((size_t)b*128 + tokblk)*8 + obl*2)*64 + lane;
            dst[base] = F0; dst[base + 64] = F1;
        } else {
            #pragma unroll
            for (int ks = 0; ks < 8; ks++)
                D = __builtin_amdgcn_mfma_f32_32x32x16_bf16(as_bf8(xf[ks]), as_bf8(wf[ks]), D, 0,0,0);
            int nb = ob - 8;
            float vb = biasL[256 + nb*32 + tl];
            #pragma unroll
            for (int r = 0; r < 16; r++) D[r] += vb;
            u32 pk[8], xch[8];
            #pragma unroll
            for (int j = 0; j < 8; j++) pk[j] = pack2(D[2*j], D[2*j+1]);
            #pragma unroll
            for (int j = 0; j < 8; j++) xch[j] = __shfl_xor(pk[j], 32);
            uint4 F0 = up ? make_uint4(xch[2],xch[3],pk[2],pk[3]) : make_uint4(pk[0],pk[1],xch[0],xch[1]);
            uint4 F1 = up ? make_uint4(xch[6],xch[7],pk[6],pk[7]) : make_uint4(pk[4],pk[5],xch[4],xch[5]);
            int it = tokblk >> 1, t2 = tokblk & 1;
            size_t base = ((((size_t)b*64 + it)*4 + nb)*4 + t2*2)*64 + lane;
            Vf[base] = F0; Vf[base + 64] = F1;
        }
    }
}

// ---------------- K3: MFMA flash attention, 8-wave blocks, 4-way in-block k-split ----------------
// grid 512 (pair = blockIdx.x&7 -> (b,ksp); qx = blockIdx.x>>3), block 512 = 8 waves
// (qh = wv>>2 in {0,1}, kh = wv&3 in {0..3}). Each wave: 32 qrows x 512 keys in 16 iters
// of 32-key tiles; the 4 kh waves sweep one contiguous 128-key window per iter.
// Barrier-free loop; end-of-kernel 3-round LDS reduce across kh.
__global__ __launch_bounds__(512, 4) void attn_kernel(const uint4* __restrict__ Qf,
                                                      const uint4* __restrict__ Kf,
                                                      const uint4* __restrict__ Vf,
                                                      uint4* __restrict__ Opart,
                                                      float* __restrict__ lsum){
    __shared__ float fsm[8192];    // 32 KB: per-qh O hand-off (4096 floats each)
    __shared__ float lred[64];
    int pair = blockIdx.x & 7, qx = blockIdx.x >> 3;
    int b = pair >> 1, ksp = pair & 1;
    int t = threadIdx.x, lane = t & 63, wv = t >> 6;
    int qh = wv >> 2, kh = wv & 3;
    const float SC2 = 0.12751744361402804f;   // (1/sqrt(128))*log2(e)
    const float B2  = -11.541560327111707f;   // -8*log2(e)

    uint4 qf[8];
    const uint4* qptr = Qf + (((size_t)b*128 + qx*2 + qh)*8)*64 + lane;
    #pragma unroll
    for (int ks = 0; ks < 8; ks++) qf[ks] = qptr[ks*64];

    f32x16 O[4];
    #pragma unroll
    for (int nb = 0; nb < 4; nb++)
        #pragma unroll
        for (int r = 0; r < 16; r++) O[nb][r] = 0.f;
    float l_i = 0.f;

    // per-wave fragment streams: iter it covers key-block tokblk = ksp*64 + it*4 + kh
    const uint4* kgw = Kf + (((size_t)b*128 + ksp*64 + kh)*8)*64 + lane;
    const uint4* vgw = Vf + ((size_t)b*64 + ksp*32 + (kh>>1))*1024 + ((kh&1)<<7) + lane;

    uint4 kf[8], vf[8];
    #pragma unroll
    for (int ks = 0; ks < 8; ks++) kf[ks] = kgw[ks*64];
    #pragma unroll
    for (int nb = 0; nb < 4; nb++){
        vf[nb*2]   = vgw[nb*256];
        vf[nb*2+1] = vgw[nb*256 + 64];
    }

    for (int it = 0; it < 16; it++){
        // S' = K·Q^T (this wave's 32 kt): split chain for ILP
        f32x16 Sa, Sb;
        #pragma unroll
        for (int r = 0; r < 16; r++){ Sa[r] = 0.f; Sb[r] = 0.f; }
        #pragma unroll
        for (int ks = 0; ks < 4; ks++)
            Sa = __builtin_amdgcn_mfma_f32_32x32x16_bf16(as_bf8(kf[ks]), as_bf8(qf[ks]), Sa, 0,0,0);
        #pragma unroll
        for (int ks = 4; ks < 8; ks++)
            Sb = __builtin_amdgcn_mfma_f32_32x32x16_bf16(as_bf8(kf[ks]), as_bf8(qf[ks]), Sb, 0,0,0);
        #pragma unroll
        for (int r = 0; r < 16; r++) Sa[r] += Sb[r];

        // prefetch next K frags (advance 4 key-blocks = 2048 uint4)
        if (it < 15){
            const uint4* kn = kgw + (it+1)*2048;
            #pragma unroll
            for (int ks = 0; ks < 8; ks++) kf[ks] = kn[ks*64];
        }

        // softmax: e = 2^(S*SC2 + B2) == exp(S*SC - 8)
        float psum = 0.f;
        u32 pk[8];
        #pragma unroll
        for (int q = 0; q < 4; q++){
            float e0 = exp2_hw(__fmaf_rn(Sa[q*4+0], SC2, B2));
            float e1 = exp2_hw(__fmaf_rn(Sa[q*4+1], SC2, B2));
            float e2 = exp2_hw(__fmaf_rn(Sa[q*4+2], SC2, B2));
            float e3 = exp2_hw(__fmaf_rn(Sa[q*4+3], SC2, B2));
            psum += (e0+e1)+(e2+e3);
            pk[2*q] = pack2(e0,e1); pk[2*q+1] = pack2(e2,e3);
        }
        psum += __shfl_xor(psum, 32);
        l_i += psum;

        u32 xch[8];
        #pragma unroll
        for (int i = 0; i < 8; i++) xch[i] = __shfl_xor(pk[i], 32);
        bool up = (lane >= 32);
        uint4 fr0 = up ? make_uint4(xch[2],xch[3],pk[2],pk[3]) : make_uint4(pk[0],pk[1],xch[0],xch[1]);
        uint4 fr1 = up ? make_uint4(xch[6],xch[7],pk[6],pk[7]) : make_uint4(pk[4],pk[5],xch[4],xch[5]);

        // PV, operands swapped: O^T[ch][qr] = V^T · P^T  (A=vf, B=fr)
        #pragma unroll
        for (int nb = 0; nb < 4; nb++){
            O[nb] = __builtin_amdgcn_mfma_f32_32x32x16_bf16(as_bf8(vf[nb*2]),   as_bf8(fr0), O[nb], 0,0,0);
            O[nb] = __builtin_amdgcn_mfma_f32_32x32x16_bf16(as_bf8(vf[nb*2+1]), as_bf8(fr1), O[nb], 0,0,0);
        }

        // prefetch next V frags
        if (it < 15){
            const uint4* vn = vgw + (it+1)*2048;
            #pragma unroll
            for (int nb = 0; nb < 4; nb++){
                vf[nb*2]   = vn[nb*256];
                vf[nb*2+1] = vn[nb*256 + 64];
            }
        }
    }

    // cross-kh reduce: 3 sequential rounds through LDS
    #pragma unroll
    for (int r = 1; r < 4; r++){
        if (kh == r){
            #pragma unroll
            for (int nb = 0; nb < 4; nb++)
                #pragma unroll
                for (int rr = 0; rr < 16; rr++)
                    fsm[(((qh*4+nb)*16) + rr)*64 + lane] = O[nb][rr];
            if (lane < 32) lred[qh*32 + lane] = l_i;
        }
        __syncthreads();
        if (kh == 0){
            #pragma unroll
            for (int nb = 0; nb < 4; nb++)
                #pragma unroll
                for (int rr = 0; rr < 16; rr++)
                    O[nb][rr] += fsm[(((qh*4+nb)*16) + rr)*64 + lane];
            l_i += lred[qh*32 + (lane & 31)];
        }
        __syncthreads();
    }

    if (kh == 0){
        if (lane < 32) lsum[((size_t)(ksp*4 + b))*HW + (qx*2+qh)*32 + lane] = l_i;
        bool up = (lane >= 32);
        uint4* oc = Opart + (size_t)ksp*262144 + (((size_t)b*128 + qx*2 + qh)*8)*64 + lane;
        #pragma unroll
        for (int nb = 0; nb < 4; nb++){
            u32 pk[8], xch[8];
            #pragma unroll
            for (int j = 0; j < 8; j++) pk[j] = pack2(O[nb][2*j], O[nb][2*j+1]);
            #pragma unroll
            for (int j = 0; j < 8; j++) xch[j] = __shfl_xor(pk[j], 32);
            uint4 F0 = up ? make_uint4(xch[2],xch[3],pk[2],pk[3]) : make_uint4(pk[0],pk[1],xch[0],xch[1]);
            uint4 F1 = up ? make_uint4(xch[6],xch[7],pk[6],pk[7]) : make_uint4(pk[4],pk[5],xch[4],xch[5]);
            oc[(nb*2)*64]     = F0;
            oc[(nb*2 + 1)*64] = F1;
        }
    }
}

// ---------------- K4: MFMA proj + inline combine + bias + residual ----------------
// grid 256, block 256. Opart chunks are B-fragment-ordered -> fully coalesced loads.
__global__ __launch_bounds__(256) void proj_kernel(const uint4* __restrict__ Op,
                                                   const float* __restrict__ lsum,
                                                   const uint4* __restrict__ Pf,
                                                   const float* __restrict__ bias,
                                                   const float* __restrict__ x,
                                                   float* __restrict__ out){
    __shared__ float biasL[128];
    int t = threadIdx.x, lane = t & 63, wv = t >> 6;
    if (t < 128) biasL[t] = bias[t];
    __syncthreads();
    int b = blockIdx.x >> 6, tk = blockIdx.x & 63;
    int tokb2 = wv & 1, obh = wv >> 1;
    int tokblk = tk*2 + tokb2;
    int h = lane >> 5, tl = lane & 31;

    int rowg = b*HW + tokblk*32 + tl;
    float inv = 1.f / (lsum[rowg] + lsum[16384 + rowg]);
    const uint4* c0p = Op + (((size_t)b*128 + tokblk)*8)*64 + lane;
    uint4 af[8];
    #pragma unroll
    for (int ks = 0; ks < 8; ks++){
        uint4 u0 = c0p[ks*64];
        uint4 u1 = c0p[262144 + ks*64];
        float v0[8], v1[8];
        unpack8(u0, v0); unpack8(u1, v1);
        u32 q[4];
        #pragma unroll
        for (int j = 0; j < 4; j++)
            q[j] = pack2((v0[2*j] + v1[2*j]) * inv, (v0[2*j+1] + v1[2*j+1]) * inv);
        af[ks] = make_uint4(q[0], q[1], q[2], q[3]);
    }

    #pragma unroll
    for (int i = 0; i < 2; i++){
        int ob = obh*2 + i;
        uint4 pf[8];
        #pragma unroll
        for (int ks = 0; ks < 8; ks++) pf[ks] = Pf[(ob*8 + ks)*64 + lane];
        f32x16 D;
        #pragma unroll
        for (int r = 0; r < 16; r++) D[r] = 0.f;
        #pragma unroll
        for (int ks = 0; ks < 8; ks++)
            D = __builtin_amdgcn_mfma_f32_32x32x16_bf16(as_bf8(pf[ks]), as_bf8(af[ks]), D, 0,0,0);
        #pragma unroll
        for (int r = 0; r < 16; r++){
            int o = ob*32 + (r&3) + 8*(r>>2) + 4*h;
            size_t gi = ((size_t)b*128 + o)*HW + tokblk*32 + tl;
            out[gi] = x[gi] + biasL[o] + D[r];
        }
    }
}

extern "C" void kernel_launch(void* const* d_in, const int* in_sizes, int n_in,
                              void* d_out, int out_size, void* d_ws, size_t ws_size,
                              hipStream_t stream){
    const float* x      = (const float*)d_in[0];
    const float* norm_w = (const float*)d_in[1];
    const float* norm_b = (const float*)d_in[2];
    const float* qkv_w  = (const float*)d_in[3];
    const float* qkv_b  = (const float*)d_in[4];
    const float* proj_w = (const float*)d_in[5];
    const float* proj_b = (const float*)d_in[6];
    float* out = (float*)d_out;

    // ws: stats 2KB | Qf 4.19MB | Kf 4.19MB | Vf 4.19MB | lsum 128KB | Wf 96KB | Pf 32KB (~12.85MB)
    char* w = (char*)d_ws;
    float* stats = (float*)w;
    uint4* Qf = (uint4*)(w + 2048);
    uint4* Kf = (uint4*)(w + 2048 + 4194304);
    uint4* Vf = (uint4*)(w + 2048 + 8388608);
    float* lsum = (float*)(w + 2048 + 12582912);
    uint4* Wf = (uint4*)(w + 2048 + 12582912 + 131072);
    uint4* Pf = (uint4*)(w + 2048 + 12582912 + 131072 + 98304);
    uint4* Opart = (uint4*)d_out;   // 2 fragment-ordered bf16 chunks = exactly 8.39 MB

    gnw_kernel<<<288, 256, 0, stream>>>(x, stats, qkv_w, proj_w, Wf, Pf);
    qkv_kernel<<<512, 256, 0, stream>>>(x, stats, norm_w, norm_b, Wf, qkv_b, Qf, Kf, Vf);
    attn_kernel<<<512, 512, 0, stream>>>(Qf, Kf, Vf, Opart, lsum);
    proj_kernel<<<256, 256, 0, stream>>>(Opart, lsum, Pf, proj_b, x, out);
}